// Round 1
// baseline (87.739 us; speedup 1.0000x reference)
//
#include <hip/hip_runtime.h>
#include <hip/hip_bf16.h>

// BQQ dims: P=2, J=32, K=32, M=128, L=16, N=128; B=512; in=kn=4096; out=jm=4096
typedef __attribute__((ext_vector_type(4))) float f32x4;
typedef __attribute__((ext_vector_type(8))) short bf16x8;

#define GLOBAL_AS __attribute__((address_space(1)))
#define LDS_AS __attribute__((address_space(3)))

static __device__ __forceinline__ unsigned short f2bf(float f) {
  __hip_bfloat16 h = __float2bfloat16(f);
  return __builtin_bit_cast(unsigned short, h);
}

static __device__ __forceinline__ void load_lds16(const void* g, void* l) {
  __builtin_amdgcn_global_load_lds((GLOBAL_AS void*)g, (LDS_AS void*)l, 16, 0, 0);
}

// ---------------- 1) per-block min/max of input (2M f32) ----------------
__global__ __launch_bounds__(256) void k_minmax_part(const float* __restrict__ x,
                                                     float* __restrict__ part) {
  int tid = blockIdx.x * 256 + threadIdx.x;  // grid 1024 -> 262144 threads, 2 quads each
  const float4* xv = (const float4*)x;
  float mn = 3.4e38f, mx = -3.4e38f;
#pragma unroll
  for (int rep = 0; rep < 2; ++rep) {
    float4 v = xv[tid + rep * 262144];
    mn = fminf(mn, fminf(fminf(v.x, v.y), fminf(v.z, v.w)));
    mx = fmaxf(mx, fmaxf(fmaxf(v.x, v.y), fmaxf(v.z, v.w)));
  }
#pragma unroll
  for (int o = 32; o > 0; o >>= 1) {
    mn = fminf(mn, __shfl_down(mn, o));
    mx = fmaxf(mx, __shfl_down(mx, o));
  }
  __shared__ float smn[4], smx[4];
  int lane = threadIdx.x & 63, w = threadIdx.x >> 6;
  if (lane == 0) { smn[w] = mn; smx[w] = mx; }
  __syncthreads();
  if (threadIdx.x == 0) {
    mn = fminf(fminf(smn[0], smn[1]), fminf(smn[2], smn[3]));
    mx = fmaxf(fmaxf(smx[0], smx[1]), fmaxf(smx[2], smx[3]));
    part[2 * blockIdx.x] = mn;
    part[2 * blockIdx.x + 1] = mx;
  }
}

// ---------------- 2) final reduce -> act_scale ----------------
__global__ __launch_bounds__(256) void k_minmax_final(const float* __restrict__ part,
                                                      float* __restrict__ scl) {
  int t = threadIdx.x;
  float mn = 3.4e38f, mx = -3.4e38f;
  for (int i = t; i < 1024; i += 256) {
    mn = fminf(mn, part[2 * i]);
    mx = fmaxf(mx, part[2 * i + 1]);
  }
#pragma unroll
  for (int o = 32; o > 0; o >>= 1) {
    mn = fminf(mn, __shfl_down(mn, o));
    mx = fmaxf(mx, __shfl_down(mx, o));
  }
  __shared__ float smn[4], smx[4];
  if ((t & 63) == 0) { smn[t >> 6] = mn; smx[t >> 6] = mx; }
  __syncthreads();
  if (t == 0) {
    mn = fminf(fminf(smn[0], smn[1]), fminf(smn[2], smn[3]));
    mx = fmaxf(fmaxf(smx[0], smx[1]), fmaxf(smx[2], smx[3]));
    float s = fmaxf((mx - mn) / 254.0f, 1e-8f);
    scl[0] = s;
  }
}

// ---------------- 3) quantize: Xi = clip(rint(x/s),±127) as bf16 (exact ints) ----------------
__global__ __launch_bounds__(256) void k_quantize(const float* __restrict__ x,
                                                  const float* __restrict__ scl,
                                                  unsigned short* __restrict__ xq) {
  int i = blockIdx.x * 256 + threadIdx.x;  // grid 2048: one float4 each
  float s = scl[0];
  float4 v = ((const float4*)x)[i];
  float a = fminf(fmaxf(rintf(v.x / s), -127.f), 127.f);
  float b = fminf(fmaxf(rintf(v.y / s), -127.f), 127.f);
  float c = fminf(fmaxf(rintf(v.z / s), -127.f), 127.f);
  float d = fminf(fmaxf(rintf(v.w / s), -127.f), 127.f);
  ((ushort4*)xq)[i] = make_ushort4(f2bf(a), f2bf(b), f2bf(c), f2bf(d));
}

// ---------------- 4) build W[jm][kn] (bf16), one block per (j,k) ----------------
// W = sum_p A0*Ysc*Zsc*(Ysign @ Zsign) + B1[m] + C1[n] + D
__global__ __launch_bounds__(256) void k_build_w(const float* __restrict__ Ysg,
                                                 const float* __restrict__ Zsg,
                                                 const float* __restrict__ Ysc,
                                                 const float* __restrict__ Zsc,
                                                 const float* __restrict__ Acoef,
                                                 unsigned short* __restrict__ W) {
  const int jk = blockIdx.x;  // j*32+k
  const int t = threadIdx.x;
  __shared__ float Yl[32][128];  // [p*16+l][m] raw signs
  __shared__ float Zl[32][128];  // [p*16+l][n] raw signs
  __shared__ float B1[128], C1[128];
  __shared__ float cf[7];  // [0..1]=A0*Ysc*Zsc, [2..3]=A1*Ysc, [4..5]=A2*Zsc, [6]=sum_p A3
  if (t < 2) {
    int idx = t * 1024 + jk;
    float ys = Ysc[idx], zs = Zsc[idx];
    cf[t] = Acoef[idx * 4 + 0] * ys * zs;
    cf[2 + t] = Acoef[idx * 4 + 1] * ys;
    cf[4 + t] = Acoef[idx * 4 + 2] * zs;
  } else if (t == 2) {
    cf[6] = Acoef[jk * 4 + 3] + Acoef[(1024 + jk) * 4 + 3];
  }
  // stage Y sign: global [p][m][l] -> Yl[p*16+l][m]  (transpose)
#pragma unroll
  for (int rep = 0; rep < 4; ++rep) {
    int q = t + rep * 256;
    int p = q >> 9, m = (q >> 2) & 127, l0 = (q & 3) * 4;
    float4 v = *(const float4*)(Ysg + (size_t)(p * 1024 + jk) * 2048 + m * 16 + l0);
    Yl[p * 16 + l0 + 0][m] = v.x;
    Yl[p * 16 + l0 + 1][m] = v.y;
    Yl[p * 16 + l0 + 2][m] = v.z;
    Yl[p * 16 + l0 + 3][m] = v.w;
  }
  // stage Z sign: global [p][l][n] -> Zl[p*16+l][n] (direct)
#pragma unroll
  for (int rep = 0; rep < 4; ++rep) {
    int q = t + rep * 256;
    int p = q >> 9, l = (q >> 5) & 15, n0 = (q & 31) * 4;
    float4 v = *(const float4*)(Zsg + (size_t)(p * 1024 + jk) * 2048 + l * 128 + n0);
    *(float4*)&Zl[p * 16 + l][n0] = v;
  }
  __syncthreads();
  // row/col corrections
  if (t < 128) {
    float s = 0.f;
#pragma unroll
    for (int pl = 0; pl < 32; ++pl) s += cf[2 + (pl >> 4)] * Yl[pl][t];
    B1[t] = s;
  } else {
    int n = t - 128;
    float s = 0.f;
#pragma unroll
    for (int pl = 0; pl < 32; ++pl) s += cf[4 + (pl >> 4)] * Zl[pl][n];
    C1[n] = s;
  }
  __syncthreads();
  // main: each thread 4 m-rows x 16 n (4 quads spread by 32 to stay bank-conflict-free)
  const int m0 = (t >> 3) * 4;
  const int n0 = (t & 7) * 4;
  float acc[4][16];
#pragma unroll
  for (int i = 0; i < 4; ++i)
#pragma unroll
    for (int g = 0; g < 16; ++g) acc[i][g] = 0.f;
  for (int pl = 0; pl < 32; ++pl) {
    float c = cf[pl >> 4];
    float4 y = *(const float4*)&Yl[pl][m0];
    float ym[4] = {y.x * c, y.y * c, y.z * c, y.w * c};
    float zr[16];
#pragma unroll
    for (int g = 0; g < 4; ++g) {
      float4 z = *(const float4*)&Zl[pl][n0 + g * 32];
      zr[g * 4 + 0] = z.x; zr[g * 4 + 1] = z.y; zr[g * 4 + 2] = z.z; zr[g * 4 + 3] = z.w;
    }
#pragma unroll
    for (int i = 0; i < 4; ++i)
#pragma unroll
      for (int g = 0; g < 16; ++g) acc[i][g] = fmaf(ym[i], zr[g], acc[i][g]);
  }
  const int j = jk >> 5, k = jk & 31;
  const float Dv = cf[6];
#pragma unroll
  for (int i = 0; i < 4; ++i) {
    int m = m0 + i;
    float bm = B1[m] + Dv;
    size_t rowoff = (size_t)(j * 128 + m) * 4096 + (size_t)(k * 128);
#pragma unroll
    for (int g = 0; g < 4; ++g) {
      int n = n0 + g * 32;
      ushort4 o = make_ushort4(f2bf(acc[i][g * 4 + 0] + bm + C1[n + 0]),
                               f2bf(acc[i][g * 4 + 1] + bm + C1[n + 1]),
                               f2bf(acc[i][g * 4 + 2] + bm + C1[n + 2]),
                               f2bf(acc[i][g * 4 + 3] + bm + C1[n + 3]));
      *(ushort4*)(W + rowoff + n) = o;
    }
  }
}

// ---------------- 5) GEMM: out[512][4096] = scale * Xi @ W^T + bias ----------------
// BM=128, BN=64, BK=64; 4 waves (2x2), wave tile 64x32; 16x16x32 bf16 MFMA.
// LDS tiles row-major [row][64 bf16] with st-style XOR swizzle (byte ^= (row&7)<<4)
// applied to the GLOBAL source column (global_load_lds dest must stay linear).
__global__ __launch_bounds__(256) void k_gemm(const unsigned short* __restrict__ Xq,
                                              const unsigned short* __restrict__ W,
                                              const float* __restrict__ scl,
                                              const float* __restrict__ bias,
                                              float* __restrict__ out) {
  __shared__ unsigned short Al[128 * 64];  // 16KB
  __shared__ unsigned short Bl[64 * 64];   // 8KB
  const int t = threadIdx.x, lane = t & 63, wid = t >> 6;
  const int bm = blockIdx.x >> 6;  // 4 row tiles
  const int bn = blockIdx.x & 63;  // 64 col tiles
  const int wm = wid >> 1, wn = wid & 1;
  f32x4 acc[4][2];
#pragma unroll
  for (int a = 0; a < 4; ++a)
#pragma unroll
    for (int b = 0; b < 2; ++b) acc[a][b] = (f32x4)(0.f);

  const int lr = lane >> 3;         // row-in-chunk 0..7
  const int lcb = (lane & 7) * 16;  // byte col in 128B row

  for (int kt = 0; kt < 64; ++kt) {
    const int k0 = kt * 64;
    // stage A (Xi tile 128x64): 16 chunks of 1KB, 4 per wave
#pragma unroll
    for (int c = 0; c < 4; ++c) {
      int chunk = wid * 4 + c;
      int r = chunk * 8 + lr;
      int colb = lcb ^ ((r & 7) << 4);
      const unsigned short* src = Xq + ((size_t)(bm * 128 + r) << 12) + k0 + (colb >> 1);
      load_lds16(src, Al + chunk * 512);
    }
    // stage B (W tile 64x64): 8 chunks, 2 per wave
#pragma unroll
    for (int c = 0; c < 2; ++c) {
      int chunk = wid * 2 + c;
      int r = chunk * 8 + lr;
      int colb = lcb ^ ((r & 7) << 4);
      const unsigned short* src = W + ((size_t)(bn * 64 + r) << 12) + k0 + (colb >> 1);
      load_lds16(src, Bl + chunk * 512);
    }
    __syncthreads();
#pragma unroll
    for (int ks = 0; ks < 2; ++ks) {
      bf16x8 af[4], bfr[2];
#pragma unroll
      for (int fm = 0; fm < 4; ++fm) {
        int r = wm * 64 + fm * 16 + (lane & 15);
        int colb = (ks * 64 + ((lane >> 4) * 16)) ^ ((r & 7) << 4);
        af[fm] = *(const bf16x8*)((const char*)Al + r * 128 + colb);
      }
#pragma unroll
      for (int fn = 0; fn < 2; ++fn) {
        int r = wn * 32 + fn * 16 + (lane & 15);
        int colb = (ks * 64 + ((lane >> 4) * 16)) ^ ((r & 7) << 4);
        bfr[fn] = *(const bf16x8*)((const char*)Bl + r * 128 + colb);
      }
#pragma unroll
      for (int fm = 0; fm < 4; ++fm)
#pragma unroll
        for (int fn = 0; fn < 2; ++fn)
          acc[fm][fn] = __builtin_amdgcn_mfma_f32_16x16x32_bf16(af[fm], bfr[fn], acc[fm][fn], 0, 0, 0);
    }
    __syncthreads();
  }
  const float s = scl[0];
#pragma unroll
  for (int fn = 0; fn < 2; ++fn) {
    int col = bn * 64 + wn * 32 + fn * 16 + (lane & 15);
    float bv = bias[col];
#pragma unroll
    for (int fm = 0; fm < 4; ++fm) {
#pragma unroll
      for (int i = 0; i < 4; ++i) {
        int row = bm * 128 + wm * 64 + fm * 16 + (lane >> 4) * 4 + i;
        out[(size_t)row * 4096 + col] = acc[fm][fn][i] * s + bv;
      }
    }
  }
}

extern "C" void kernel_launch(void* const* d_in, const int* in_sizes, int n_in,
                              void* d_out, int out_size, void* d_ws, size_t ws_size,
                              hipStream_t stream) {
  const float* x    = (const float*)d_in[0];  // (1,512,4096)
  const float* Ysg  = (const float*)d_in[1];  // (2,32,32,128,16)
  const float* Zsg  = (const float*)d_in[2];  // (2,32,32,16,128)
  const float* Ysc  = (const float*)d_in[3];  // (2,32,32)
  const float* Zsc  = (const float*)d_in[4];  // (2,32,32)
  const float* A    = (const float*)d_in[5];  // (2,32,32,4)
  const float* bias = (const float*)d_in[6];  // (4096,)
  float* out = (float*)d_out;

  char* ws = (char*)d_ws;
  float* scl  = (float*)ws;                       // [0] act_scale
  float* part = (float*)(ws + 256);               // 2048 f32 partials
  unsigned short* Xq = (unsigned short*)(ws + 65536);                       // 4MB bf16
  unsigned short* W  = (unsigned short*)(ws + 65536 + (size_t)4194304);     // 32MB bf16

  k_minmax_part<<<dim3(1024), dim3(256), 0, stream>>>(x, part);
  k_minmax_final<<<dim3(1), dim3(256), 0, stream>>>(part, scl);
  k_quantize<<<dim3(2048), dim3(256), 0, stream>>>(x, scl, Xq);
  k_build_w<<<dim3(1024), dim3(256), 0, stream>>>(Ysg, Zsg, Ysc, Zsc, A, W);
  k_gemm<<<dim3(256), dim3(256), 0, stream>>>(Xq, W, scl, bias, out);
}

// Round 2
// 84.839 us; speedup vs baseline: 1.0342x; 1.0342x over previous
//
#include <hip/hip_runtime.h>
#include <hip/hip_bf16.h>

// BQQ dims: P=2, J=32, K=32, M=128, L=16, N=128; B=512; in=kn=4096; out=jm=4096
typedef __attribute__((ext_vector_type(4))) float f32x4;
typedef __attribute__((ext_vector_type(8))) short bf16x8;

#define GLOBAL_AS __attribute__((address_space(1)))
#define LDS_AS __attribute__((address_space(3)))

static __device__ __forceinline__ unsigned short f2bf(float f) {
  __hip_bfloat16 h = __float2bfloat16(f);
  return __builtin_bit_cast(unsigned short, h);
}

static __device__ __forceinline__ void load_lds16(const void* g, void* l) {
  __builtin_amdgcn_global_load_lds((GLOBAL_AS void*)g, (LDS_AS void*)l, 16, 0, 0);
}

// ---------------- 1) per-block min/max of input (2M f32), 256 blocks ----------------
__global__ __launch_bounds__(256) void k_minmax_part(const float* __restrict__ x,
                                                     float* __restrict__ part) {
  int tid = blockIdx.x * 256 + threadIdx.x;  // 65536 threads, 8 float4 each
  const float4* xv = (const float4*)x;
  float mn = 3.4e38f, mx = -3.4e38f;
#pragma unroll
  for (int rep = 0; rep < 8; ++rep) {
    float4 v = xv[tid + rep * 65536];
    mn = fminf(mn, fminf(fminf(v.x, v.y), fminf(v.z, v.w)));
    mx = fmaxf(mx, fmaxf(fmaxf(v.x, v.y), fmaxf(v.z, v.w)));
  }
#pragma unroll
  for (int o = 32; o > 0; o >>= 1) {
    mn = fminf(mn, __shfl_down(mn, o));
    mx = fmaxf(mx, __shfl_down(mx, o));
  }
  __shared__ float smn[4], smx[4];
  int lane = threadIdx.x & 63, w = threadIdx.x >> 6;
  if (lane == 0) { smn[w] = mn; smx[w] = mx; }
  __syncthreads();
  if (threadIdx.x == 0) {
    mn = fminf(fminf(smn[0], smn[1]), fminf(smn[2], smn[3]));
    mx = fmaxf(fmaxf(smx[0], smx[1]), fmaxf(smx[2], smx[3]));
    part[2 * blockIdx.x] = mn;
    part[2 * blockIdx.x + 1] = mx;
  }
}

// ---------------- 2) fused: blocks 0..1023 = build W; 1024..3071 = quantize ----------------
// W[jm][kn] = sum_p A0*Ysc*Zsc*(Ysign @ Zsign) + B1[m] + C1[n] + D   (bf16)
// Xi = clip(rint(x/s),+-127) stored as bf16 (exact integers)
__global__ __launch_bounds__(256) void k_fused(const float* __restrict__ x,
                                               const float* __restrict__ part,
                                               const float* __restrict__ Ysg,
                                               const float* __restrict__ Zsg,
                                               const float* __restrict__ Ysc,
                                               const float* __restrict__ Zsc,
                                               const float* __restrict__ Acoef,
                                               float* __restrict__ scl,
                                               unsigned short* __restrict__ xq,
                                               unsigned short* __restrict__ W) {
  const int t = threadIdx.x;
  if (blockIdx.x < 1024) {
    // ---- build_w ----
    const int jk = blockIdx.x;  // j*32+k
    __shared__ float Yl[32][128];  // [p*16+l][m] raw signs
    __shared__ float Zl[32][128];  // [p*16+l][n] raw signs
    __shared__ float B1[128], C1[128];
    __shared__ float cf[7];
    if (t < 2) {
      int idx = t * 1024 + jk;
      float ys = Ysc[idx], zs = Zsc[idx];
      cf[t] = Acoef[idx * 4 + 0] * ys * zs;
      cf[2 + t] = Acoef[idx * 4 + 1] * ys;
      cf[4 + t] = Acoef[idx * 4 + 2] * zs;
    } else if (t == 2) {
      cf[6] = Acoef[jk * 4 + 3] + Acoef[(1024 + jk) * 4 + 3];
    }
#pragma unroll
    for (int rep = 0; rep < 4; ++rep) {
      int q = t + rep * 256;
      int p = q >> 9, m = (q >> 2) & 127, l0 = (q & 3) * 4;
      float4 v = *(const float4*)(Ysg + (size_t)(p * 1024 + jk) * 2048 + m * 16 + l0);
      Yl[p * 16 + l0 + 0][m] = v.x;
      Yl[p * 16 + l0 + 1][m] = v.y;
      Yl[p * 16 + l0 + 2][m] = v.z;
      Yl[p * 16 + l0 + 3][m] = v.w;
    }
#pragma unroll
    for (int rep = 0; rep < 4; ++rep) {
      int q = t + rep * 256;
      int p = q >> 9, l = (q >> 5) & 15, n0 = (q & 31) * 4;
      float4 v = *(const float4*)(Zsg + (size_t)(p * 1024 + jk) * 2048 + l * 128 + n0);
      *(float4*)&Zl[p * 16 + l][n0] = v;
    }
    __syncthreads();
    if (t < 128) {
      float s = 0.f;
#pragma unroll
      for (int pl = 0; pl < 32; ++pl) s += cf[2 + (pl >> 4)] * Yl[pl][t];
      B1[t] = s;
    } else {
      int n = t - 128;
      float s = 0.f;
#pragma unroll
      for (int pl = 0; pl < 32; ++pl) s += cf[4 + (pl >> 4)] * Zl[pl][n];
      C1[n] = s;
    }
    __syncthreads();
    const int m0 = (t >> 3) * 4;
    const int n0 = (t & 7) * 4;
    float acc[4][16];
#pragma unroll
    for (int i = 0; i < 4; ++i)
#pragma unroll
      for (int g = 0; g < 16; ++g) acc[i][g] = 0.f;
    for (int pl = 0; pl < 32; ++pl) {
      float c = cf[pl >> 4];
      float4 y = *(const float4*)&Yl[pl][m0];
      float ym[4] = {y.x * c, y.y * c, y.z * c, y.w * c};
      float zr[16];
#pragma unroll
      for (int g = 0; g < 4; ++g) {
        float4 z = *(const float4*)&Zl[pl][n0 + g * 32];
        zr[g * 4 + 0] = z.x; zr[g * 4 + 1] = z.y; zr[g * 4 + 2] = z.z; zr[g * 4 + 3] = z.w;
      }
#pragma unroll
      for (int i = 0; i < 4; ++i)
#pragma unroll
        for (int g = 0; g < 16; ++g) acc[i][g] = fmaf(ym[i], zr[g], acc[i][g]);
    }
    const int j = jk >> 5, k = jk & 31;
    const float Dv = cf[6];
#pragma unroll
    for (int i = 0; i < 4; ++i) {
      int m = m0 + i;
      float bm = B1[m] + Dv;
      size_t rowoff = (size_t)(j * 128 + m) * 4096 + (size_t)(k * 128);
#pragma unroll
      for (int g = 0; g < 4; ++g) {
        int n = n0 + g * 32;
        ushort4 o = make_ushort4(f2bf(acc[i][g * 4 + 0] + bm + C1[n + 0]),
                                 f2bf(acc[i][g * 4 + 1] + bm + C1[n + 1]),
                                 f2bf(acc[i][g * 4 + 2] + bm + C1[n + 2]),
                                 f2bf(acc[i][g * 4 + 3] + bm + C1[n + 3]));
        *(ushort4*)(W + rowoff + n) = o;
      }
    }
  } else {
    // ---- quantize (with in-block redundant scale reduce) ----
    const int qb = blockIdx.x - 1024;
    float2 v2 = ((const float2*)part)[t];  // 256 float2 = 512 partials
    float mn = v2.x, mx = v2.y;
#pragma unroll
    for (int o = 32; o > 0; o >>= 1) {
      mn = fminf(mn, __shfl_down(mn, o));
      mx = fmaxf(mx, __shfl_down(mx, o));
    }
    __shared__ float smn2[4], smx2[4], ssc[1];
    int lane = t & 63, w = t >> 6;
    if (lane == 0) { smn2[w] = mn; smx2[w] = mx; }
    __syncthreads();
    if (t == 0) {
      mn = fminf(fminf(smn2[0], smn2[1]), fminf(smn2[2], smn2[3]));
      mx = fmaxf(fmaxf(smx2[0], smx2[1]), fmaxf(smx2[2], smx2[3]));
      ssc[0] = fmaxf((mx - mn) / 254.0f, 1e-8f);
      if (qb == 0) scl[0] = ssc[0];
    }
    __syncthreads();
    const float s = ssc[0];
    int i = qb * 256 + t;
    float4 v = ((const float4*)x)[i];
    float a = fminf(fmaxf(rintf(v.x / s), -127.f), 127.f);
    float b = fminf(fmaxf(rintf(v.y / s), -127.f), 127.f);
    float c = fminf(fmaxf(rintf(v.z / s), -127.f), 127.f);
    float d = fminf(fmaxf(rintf(v.w / s), -127.f), 127.f);
    ((ushort4*)xq)[i] = make_ushort4(f2bf(a), f2bf(b), f2bf(c), f2bf(d));
  }
}

// ---------------- 3) GEMM: out[512][4096] = scale * Xi @ W^T + bias ----------------
// BM=128, BN=64, BK=64; 8 waves (4x2), wave tile 32x32; 16x16x32 bf16 MFMA.
// Double-buffered LDS (48KB), 2-phase schedule: STAGE(next) issued before
// ds_read+MFMA(cur), ONE barrier per K-step. XOR swizzle byte^((row&7)<<4)
// applied on the GLOBAL source column (gload_lds dest stays linear) and on reads.
__global__ __launch_bounds__(512) void k_gemm(const unsigned short* __restrict__ Xq,
                                              const unsigned short* __restrict__ W,
                                              const float* __restrict__ scl,
                                              const float* __restrict__ bias,
                                              float* __restrict__ out) {
  __shared__ unsigned short Al[2][128 * 64];  // 2 x 16KB
  __shared__ unsigned short Bl[2][64 * 64];   // 2 x 8KB
  const int t = threadIdx.x, lane = t & 63, wid = t >> 6;  // wid 0..7
  // XCD-chunked swizzle: grid 256 % 8 == 0, bijective. XCD x owns wg [32x,32x+32).
  const int wg = (blockIdx.x & 7) * 32 + (blockIdx.x >> 3);
  const int bm = wg & 3;    // 4 row tiles (M=512)
  const int bn = wg >> 2;   // 64 col tiles -> 8 consecutive bn per XCD (4MB W panel)
  const int wm = wid >> 1, wn = wid & 1;  // wave tile 32x32
  f32x4 acc[2][2];
#pragma unroll
  for (int a = 0; a < 2; ++a)
#pragma unroll
    for (int b = 0; b < 2; ++b) acc[a][b] = (f32x4)(0.f);

  const int lr = lane >> 3;         // row-in-chunk 0..7
  const int lcb = (lane & 7) * 16;  // byte col in 128B row

  auto STAGE = [&](int buf, int kt) {
    const int k0 = kt * 64;
    // A tile 128x64: 16 chunks of 1KB, 2 per wave
#pragma unroll
    for (int c = 0; c < 2; ++c) {
      int chunk = wid * 2 + c;
      int r = chunk * 8 + lr;
      int colb = lcb ^ ((r & 7) << 4);
      load_lds16(Xq + ((size_t)(bm * 128 + r) << 12) + k0 + (colb >> 1), &Al[buf][chunk * 512]);
    }
    // B tile 64x64: 8 chunks, 1 per wave
    {
      int r = wid * 8 + lr;
      int colb = lcb ^ ((r & 7) << 4);
      load_lds16(W + ((size_t)(bn * 64 + r) << 12) + k0 + (colb >> 1), &Bl[buf][wid * 512]);
    }
  };

  auto COMPUTE = [&](int buf) {
#pragma unroll
    for (int ks = 0; ks < 2; ++ks) {
      bf16x8 af[2], bfr[2];
#pragma unroll
      for (int fm = 0; fm < 2; ++fm) {
        int r = wm * 32 + fm * 16 + (lane & 15);
        int colb = (ks * 64 + ((lane >> 4) * 16)) ^ ((r & 7) << 4);
        af[fm] = *(const bf16x8*)((const char*)&Al[buf][0] + r * 128 + colb);
      }
#pragma unroll
      for (int fn = 0; fn < 2; ++fn) {
        int r = wn * 32 + fn * 16 + (lane & 15);
        int colb = (ks * 64 + ((lane >> 4) * 16)) ^ ((r & 7) << 4);
        bfr[fn] = *(const bf16x8*)((const char*)&Bl[buf][0] + r * 128 + colb);
      }
#pragma unroll
      for (int fm = 0; fm < 2; ++fm)
#pragma unroll
        for (int fn = 0; fn < 2; ++fn)
          acc[fm][fn] = __builtin_amdgcn_mfma_f32_16x16x32_bf16(af[fm], bfr[fn], acc[fm][fn], 0, 0, 0);
    }
  };

  STAGE(0, 0);
  __syncthreads();  // drains vmcnt -> buf0 ready
  int cur = 0;
  for (int kt = 0; kt < 63; ++kt) {
    STAGE(cur ^ 1, kt + 1);  // issue next-tile loads FIRST (latency hides under step)
    COMPUTE(cur);
    __syncthreads();         // one barrier per K-step; drains stage into cur^1
    cur ^= 1;
  }
  COMPUTE(cur);

  const float s = scl[0];
#pragma unroll
  for (int fn = 0; fn < 2; ++fn) {
    int col = bn * 64 + wn * 32 + fn * 16 + (lane & 15);
    float bv = bias[col];
#pragma unroll
    for (int fm = 0; fm < 2; ++fm) {
#pragma unroll
      for (int i = 0; i < 4; ++i) {
        int row = bm * 128 + wm * 32 + fm * 16 + (lane >> 4) * 4 + i;
        out[(size_t)row * 4096 + col] = acc[fm][fn][i] * s + bv;
      }
    }
  }
}

extern "C" void kernel_launch(void* const* d_in, const int* in_sizes, int n_in,
                              void* d_out, int out_size, void* d_ws, size_t ws_size,
                              hipStream_t stream) {
  const float* x    = (const float*)d_in[0];  // (1,512,4096)
  const float* Ysg  = (const float*)d_in[1];  // (2,32,32,128,16)
  const float* Zsg  = (const float*)d_in[2];  // (2,32,32,16,128)
  const float* Ysc  = (const float*)d_in[3];  // (2,32,32)
  const float* Zsc  = (const float*)d_in[4];  // (2,32,32)
  const float* A    = (const float*)d_in[5];  // (2,32,32,4)
  const float* bias = (const float*)d_in[6];  // (4096,)
  float* out = (float*)d_out;

  char* ws = (char*)d_ws;
  float* scl  = (float*)ws;                  // [0] act_scale
  float* part = (float*)(ws + 256);          // 512 f32 partials
  unsigned short* Xq = (unsigned short*)(ws + 65536);                    // 4MB bf16
  unsigned short* W  = (unsigned short*)(ws + 65536 + (size_t)4194304);  // 32MB bf16

  k_minmax_part<<<dim3(256), dim3(256), 0, stream>>>(x, part);
  k_fused<<<dim3(3072), dim3(256), 0, stream>>>(x, part, Ysg, Zsg, Ysc, Zsc, A, scl, Xq, W);
  k_gemm<<<dim3(256), dim3(512), 0, stream>>>(Xq, W, scl, bias, out);
}

// Round 3
// 79.303 us; speedup vs baseline: 1.1064x; 1.0698x over previous
//
#include <hip/hip_runtime.h>
#include <hip/hip_bf16.h>

// BQQ dims: P=2, J=32, K=32, M=128, L=16, N=128; B=512; in=kn=4096; out=jm=4096
typedef __attribute__((ext_vector_type(4))) float f32x4;
typedef __attribute__((ext_vector_type(8))) short bf16x8;

#define GLOBAL_AS __attribute__((address_space(1)))
#define LDS_AS __attribute__((address_space(3)))

static __device__ __forceinline__ unsigned short f2bf(float f) {
  __hip_bfloat16 h = __float2bfloat16(f);
  return __builtin_bit_cast(unsigned short, h);
}

static __device__ __forceinline__ void load_lds16(const void* g, void* l) {
  __builtin_amdgcn_global_load_lds((GLOBAL_AS void*)g, (LDS_AS void*)l, 16, 0, 0);
}

// ---------------- 1) per-block min/max of input (2M f32), 256 blocks ----------------
__global__ __launch_bounds__(256) void k_minmax_part(const float* __restrict__ x,
                                                     float* __restrict__ part) {
  int tid = blockIdx.x * 256 + threadIdx.x;  // 65536 threads, 8 float4 each
  const float4* xv = (const float4*)x;
  float mn = 3.4e38f, mx = -3.4e38f;
#pragma unroll
  for (int rep = 0; rep < 8; ++rep) {
    float4 v = xv[tid + rep * 65536];
    mn = fminf(mn, fminf(fminf(v.x, v.y), fminf(v.z, v.w)));
    mx = fmaxf(mx, fmaxf(fmaxf(v.x, v.y), fmaxf(v.z, v.w)));
  }
#pragma unroll
  for (int o = 32; o > 0; o >>= 1) {
    mn = fminf(mn, __shfl_down(mn, o));
    mx = fmaxf(mx, __shfl_down(mx, o));
  }
  __shared__ float smn[4], smx[4];
  int lane = threadIdx.x & 63, w = threadIdx.x >> 6;
  if (lane == 0) { smn[w] = mn; smx[w] = mx; }
  __syncthreads();
  if (threadIdx.x == 0) {
    mn = fminf(fminf(smn[0], smn[1]), fminf(smn[2], smn[3]));
    mx = fmaxf(fmaxf(smx[0], smx[1]), fmaxf(smx[2], smx[3]));
    part[2 * blockIdx.x] = mn;
    part[2 * blockIdx.x + 1] = mx;
  }
}

// ---------------- 2) fused: blocks 0..1023 = build W; 1024..3071 = quantize ----------------
__global__ __launch_bounds__(256) void k_fused(const float* __restrict__ x,
                                               const float* __restrict__ part,
                                               const float* __restrict__ Ysg,
                                               const float* __restrict__ Zsg,
                                               const float* __restrict__ Ysc,
                                               const float* __restrict__ Zsc,
                                               const float* __restrict__ Acoef,
                                               float* __restrict__ scl,
                                               unsigned short* __restrict__ xq,
                                               unsigned short* __restrict__ W) {
  const int t = threadIdx.x;
  if (blockIdx.x < 1024) {
    // ---- build_w ----
    const int jk = blockIdx.x;  // j*32+k
    __shared__ float Yl[32][128];  // [p*16+l][m] raw signs
    __shared__ float Zl[32][128];  // [p*16+l][n] raw signs
    __shared__ float B1[128], C1[128];
    __shared__ float cf[7];
    if (t < 2) {
      int idx = t * 1024 + jk;
      float ys = Ysc[idx], zs = Zsc[idx];
      cf[t] = Acoef[idx * 4 + 0] * ys * zs;
      cf[2 + t] = Acoef[idx * 4 + 1] * ys;
      cf[4 + t] = Acoef[idx * 4 + 2] * zs;
    } else if (t == 2) {
      cf[6] = Acoef[jk * 4 + 3] + Acoef[(1024 + jk) * 4 + 3];
    }
#pragma unroll
    for (int rep = 0; rep < 4; ++rep) {
      int q = t + rep * 256;
      int p = q >> 9, m = (q >> 2) & 127, l0 = (q & 3) * 4;
      float4 v = *(const float4*)(Ysg + (size_t)(p * 1024 + jk) * 2048 + m * 16 + l0);
      Yl[p * 16 + l0 + 0][m] = v.x;
      Yl[p * 16 + l0 + 1][m] = v.y;
      Yl[p * 16 + l0 + 2][m] = v.z;
      Yl[p * 16 + l0 + 3][m] = v.w;
    }
#pragma unroll
    for (int rep = 0; rep < 4; ++rep) {
      int q = t + rep * 256;
      int p = q >> 9, l = (q >> 5) & 15, n0 = (q & 31) * 4;
      float4 v = *(const float4*)(Zsg + (size_t)(p * 1024 + jk) * 2048 + l * 128 + n0);
      *(float4*)&Zl[p * 16 + l][n0] = v;
    }
    __syncthreads();
    if (t < 128) {
      float s = 0.f;
#pragma unroll
      for (int pl = 0; pl < 32; ++pl) s += cf[2 + (pl >> 4)] * Yl[pl][t];
      B1[t] = s;
    } else {
      int n = t - 128;
      float s = 0.f;
#pragma unroll
      for (int pl = 0; pl < 32; ++pl) s += cf[4 + (pl >> 4)] * Zl[pl][n];
      C1[n] = s;
    }
    __syncthreads();
    const int m0 = (t >> 3) * 4;
    const int n0 = (t & 7) * 4;
    float acc[4][16];
#pragma unroll
    for (int i = 0; i < 4; ++i)
#pragma unroll
      for (int g = 0; g < 16; ++g) acc[i][g] = 0.f;
    for (int pl = 0; pl < 32; ++pl) {
      float c = cf[pl >> 4];
      float4 y = *(const float4*)&Yl[pl][m0];
      float ym[4] = {y.x * c, y.y * c, y.z * c, y.w * c};
      float zr[16];
#pragma unroll
      for (int g = 0; g < 4; ++g) {
        float4 z = *(const float4*)&Zl[pl][n0 + g * 32];
        zr[g * 4 + 0] = z.x; zr[g * 4 + 1] = z.y; zr[g * 4 + 2] = z.z; zr[g * 4 + 3] = z.w;
      }
#pragma unroll
      for (int i = 0; i < 4; ++i)
#pragma unroll
        for (int g = 0; g < 16; ++g) acc[i][g] = fmaf(ym[i], zr[g], acc[i][g]);
    }
    const int j = jk >> 5, k = jk & 31;
    const float Dv = cf[6];
#pragma unroll
    for (int i = 0; i < 4; ++i) {
      int m = m0 + i;
      float bm = B1[m] + Dv;
      size_t rowoff = (size_t)(j * 128 + m) * 4096 + (size_t)(k * 128);
#pragma unroll
      for (int g = 0; g < 4; ++g) {
        int n = n0 + g * 32;
        ushort4 o = make_ushort4(f2bf(acc[i][g * 4 + 0] + bm + C1[n + 0]),
                                 f2bf(acc[i][g * 4 + 1] + bm + C1[n + 1]),
                                 f2bf(acc[i][g * 4 + 2] + bm + C1[n + 2]),
                                 f2bf(acc[i][g * 4 + 3] + bm + C1[n + 3]));
        *(ushort4*)(W + rowoff + n) = o;
      }
    }
  } else {
    // ---- quantize (with in-block redundant scale reduce) ----
    const int qb = blockIdx.x - 1024;
    float2 v2 = ((const float2*)part)[t];  // 256 float2 = 512 partials
    float mn = v2.x, mx = v2.y;
#pragma unroll
    for (int o = 32; o > 0; o >>= 1) {
      mn = fminf(mn, __shfl_down(mn, o));
      mx = fmaxf(mx, __shfl_down(mx, o));
    }
    __shared__ float smn2[4], smx2[4], ssc[1];
    int lane = t & 63, w = t >> 6;
    if (lane == 0) { smn2[w] = mn; smx2[w] = mx; }
    __syncthreads();
    if (t == 0) {
      mn = fminf(fminf(smn2[0], smn2[1]), fminf(smn2[2], smn2[3]));
      mx = fmaxf(fmaxf(smx2[0], smx2[1]), fmaxf(smx2[2], smx2[3]));
      ssc[0] = fmaxf((mx - mn) / 254.0f, 1e-8f);
      if (qb == 0) scl[0] = ssc[0];
    }
    __syncthreads();
    const float s = ssc[0];
    int i = qb * 256 + t;
    float4 v = ((const float4*)x)[i];
    float a = fminf(fmaxf(rintf(v.x / s), -127.f), 127.f);
    float b = fminf(fmaxf(rintf(v.y / s), -127.f), 127.f);
    float c = fminf(fmaxf(rintf(v.z / s), -127.f), 127.f);
    float d = fminf(fmaxf(rintf(v.w / s), -127.f), 127.f);
    ((ushort4*)xq)[i] = make_ushort4(f2bf(a), f2bf(b), f2bf(c), f2bf(d));
  }
}

// ---------------- 3) GEMM: out[512][4096] = scale * Xi @ W^T + bias ----------------
// BM=128, BN=64, BK=64; 8 waves (4x2), wave tile 32x32; 16x16x32 bf16 MFMA.
// 4-buffer LDS ring (96KB), prefetch depth 3, raw s_barrier + COUNTED vmcnt(9)
// (never 0 in the loop) so 9 global_load_lds stay in flight across barriers.
// Uniform 3 loads/wave/iter (dummy wrap stages at tail keep vmcnt math constant).
__global__ __launch_bounds__(512) void k_gemm(const unsigned short* __restrict__ Xq,
                                              const unsigned short* __restrict__ W,
                                              const float* __restrict__ scl,
                                              const float* __restrict__ bias,
                                              float* __restrict__ out) {
  __shared__ unsigned short Al[4][128 * 64];  // 4 x 16KB
  __shared__ unsigned short Bl[4][64 * 64];   // 4 x 8KB
  const int t = threadIdx.x, lane = t & 63, wid = t >> 6;  // wid 0..7
  // XCD-chunked bijective swizzle (grid 256 % 8 == 0): XCD x owns wg [32x,32x+32).
  const int wg = (blockIdx.x & 7) * 32 + (blockIdx.x >> 3);
  const int bm = wg & 3;    // 4 row tiles (M=512)
  const int bn = wg >> 2;   // 64 col tiles -> 8 consecutive bn per XCD
  const int wm = wid >> 1, wn = wid & 1;  // wave tile 32x32
  f32x4 acc[2][2];
#pragma unroll
  for (int a = 0; a < 2; ++a)
#pragma unroll
    for (int b = 0; b < 2; ++b) acc[a][b] = (f32x4)(0.f);

  const int lr = lane >> 3;         // row-in-chunk 0..7
  const int lcb = (lane & 7) * 16;  // byte col in 128B row

  auto STAGE = [&](int buf, int kt) {
    const int k0 = kt * 64;
    // A tile 128x64: 16 chunks of 1KB, 2 per wave
#pragma unroll
    for (int c = 0; c < 2; ++c) {
      int chunk = wid * 2 + c;
      int r = chunk * 8 + lr;
      int colb = lcb ^ ((r & 7) << 4);
      load_lds16(Xq + ((size_t)(bm * 128 + r) << 12) + k0 + (colb >> 1), &Al[buf][chunk * 512]);
    }
    // B tile 64x64: 8 chunks, 1 per wave
    {
      int r = wid * 8 + lr;
      int colb = lcb ^ ((r & 7) << 4);
      load_lds16(W + ((size_t)(bn * 64 + r) << 12) + k0 + (colb >> 1), &Bl[buf][wid * 512]);
    }
  };

  auto COMPUTE = [&](int buf) {
#pragma unroll
    for (int ks = 0; ks < 2; ++ks) {
      bf16x8 af[2], bfr[2];
#pragma unroll
      for (int fm = 0; fm < 2; ++fm) {
        int r = wm * 32 + fm * 16 + (lane & 15);
        int colb = (ks * 64 + ((lane >> 4) * 16)) ^ ((r & 7) << 4);
        af[fm] = *(const bf16x8*)((const char*)&Al[buf][0] + r * 128 + colb);
      }
#pragma unroll
      for (int fn = 0; fn < 2; ++fn) {
        int r = wn * 32 + fn * 16 + (lane & 15);
        int colb = (ks * 64 + ((lane >> 4) * 16)) ^ ((r & 7) << 4);
        bfr[fn] = *(const bf16x8*)((const char*)&Bl[buf][0] + r * 128 + colb);
      }
#pragma unroll
      for (int fm = 0; fm < 2; ++fm)
#pragma unroll
        for (int fn = 0; fn < 2; ++fn)
          acc[fm][fn] = __builtin_amdgcn_mfma_f32_16x16x32_bf16(af[fm], bfr[fn], acc[fm][fn], 0, 0, 0);
    }
  };

  // prologue: fill 3 buffers (9 loads outstanding per wave)
  STAGE(0, 0);
  STAGE(1, 1);
  STAGE(2, 2);
  for (int t64 = 0; t64 < 64; ++t64) {
    // stage 3 ahead; tail iters re-stage kt&63 (dummy, buffer never read again)
    STAGE((t64 + 3) & 3, (t64 + 3) & 63);
    __builtin_amdgcn_sched_barrier(0);
    asm volatile("s_waitcnt vmcnt(9)" ::: "memory");  // stage(t64) landed; 9 stay in flight
    __builtin_amdgcn_sched_barrier(0);
    __builtin_amdgcn_s_barrier();                     // all waves: buf[t64&3] ready
    __builtin_amdgcn_sched_barrier(0);
    COMPUTE(t64 & 3);
    __builtin_amdgcn_sched_barrier(0);
    __builtin_amdgcn_s_barrier();                     // reads done before buf reuse
  }

  const float s = scl[0];
#pragma unroll
  for (int fn = 0; fn < 2; ++fn) {
    int col = bn * 64 + wn * 32 + fn * 16 + (lane & 15);
    float bv = bias[col];
#pragma unroll
    for (int fm = 0; fm < 2; ++fm) {
#pragma unroll
      for (int i = 0; i < 4; ++i) {
        int row = bm * 128 + wm * 32 + fm * 16 + (lane >> 4) * 4 + i;
        out[(size_t)row * 4096 + col] = acc[fm][fn][i] * s + bv;
      }
    }
  }
}

extern "C" void kernel_launch(void* const* d_in, const int* in_sizes, int n_in,
                              void* d_out, int out_size, void* d_ws, size_t ws_size,
                              hipStream_t stream) {
  const float* x    = (const float*)d_in[0];  // (1,512,4096)
  const float* Ysg  = (const float*)d_in[1];  // (2,32,32,128,16)
  const float* Zsg  = (const float*)d_in[2];  // (2,32,32,16,128)
  const float* Ysc  = (const float*)d_in[3];  // (2,32,32)
  const float* Zsc  = (const float*)d_in[4];  // (2,32,32)
  const float* A    = (const float*)d_in[5];  // (2,32,32,4)
  const float* bias = (const float*)d_in[6];  // (4096,)
  float* out = (float*)d_out;

  char* ws = (char*)d_ws;
  float* scl  = (float*)ws;                  // [0] act_scale
  float* part = (float*)(ws + 256);          // 512 f32 partials
  unsigned short* Xq = (unsigned short*)(ws + 65536);                    // 4MB bf16
  unsigned short* W  = (unsigned short*)(ws + 65536 + (size_t)4194304);  // 32MB bf16

  k_minmax_part<<<dim3(256), dim3(256), 0, stream>>>(x, part);
  k_fused<<<dim3(3072), dim3(256), 0, stream>>>(x, part, Ysg, Zsg, Ysc, Zsc, A, scl, Xq, W);
  k_gemm<<<dim3(256), dim3(512), 0, stream>>>(Xq, W, scl, bias, out);
}

// Round 4
// 65.187 us; speedup vs baseline: 1.3460x; 1.2166x over previous
//
#include <hip/hip_runtime.h>
#include <hip/hip_bf16.h>

// BQQ dims: P=2, J=32, K=32, M=128, L=16, N=128; B=512; in=kn=4096; out=jm=4096
typedef __attribute__((ext_vector_type(4))) float f32x4;
typedef __attribute__((ext_vector_type(8))) short bf16x8;

#define GLOBAL_AS __attribute__((address_space(1)))
#define LDS_AS __attribute__((address_space(3)))

static __device__ __forceinline__ unsigned short f2bf(float f) {
  __hip_bfloat16 h = __float2bfloat16(f);
  return __builtin_bit_cast(unsigned short, h);
}
static __device__ __forceinline__ float bf2f(unsigned short u) {
  unsigned int v = ((unsigned int)u) << 16;
  return __builtin_bit_cast(float, v);
}
static __device__ __forceinline__ void load_lds16(const void* g, void* l) {
  __builtin_amdgcn_global_load_lds((GLOBAL_AS void*)g, (LDS_AS void*)l, 16, 0, 0);
}

// ---------------- 1) per-block min/max of input (2M f32), 256 blocks ----------------
__global__ __launch_bounds__(256) void k_minmax_part(const float* __restrict__ x,
                                                     float* __restrict__ part) {
  int tid = blockIdx.x * 256 + threadIdx.x;  // 65536 threads, 8 float4 each
  const float4* xv = (const float4*)x;
  float mn = 3.4e38f, mx = -3.4e38f;
#pragma unroll
  for (int rep = 0; rep < 8; ++rep) {
    float4 v = xv[tid + rep * 65536];
    mn = fminf(mn, fminf(fminf(v.x, v.y), fminf(v.z, v.w)));
    mx = fmaxf(mx, fmaxf(fmaxf(v.x, v.y), fmaxf(v.z, v.w)));
  }
#pragma unroll
  for (int o = 32; o > 0; o >>= 1) {
    mn = fminf(mn, __shfl_down(mn, o));
    mx = fmaxf(mx, __shfl_down(mx, o));
  }
  __shared__ float smn[4], smx[4];
  int lane = threadIdx.x & 63, w = threadIdx.x >> 6;
  if (lane == 0) { smn[w] = mn; smx[w] = mx; }
  __syncthreads();
  if (threadIdx.x == 0) {
    mn = fminf(fminf(smn[0], smn[1]), fminf(smn[2], smn[3]));
    mx = fmaxf(fmaxf(smx[0], smx[1]), fmaxf(smx[2], smx[3]));
    part[2 * blockIdx.x] = mn;
    part[2 * blockIdx.x + 1] = mx;
  }
}

// ---------------- 2) fused: blocks 0..1023 = build W; 1024..3071 = quantize ----------------
__global__ __launch_bounds__(256) void k_fused(const float* __restrict__ x,
                                               const float* __restrict__ part,
                                               const float* __restrict__ Ysg,
                                               const float* __restrict__ Zsg,
                                               const float* __restrict__ Ysc,
                                               const float* __restrict__ Zsc,
                                               const float* __restrict__ Acoef,
                                               float* __restrict__ scl,
                                               unsigned short* __restrict__ xq,
                                               unsigned short* __restrict__ W) {
  const int t = threadIdx.x;
  if (blockIdx.x < 1024) {
    // ---- build_w ----
    const int jk = blockIdx.x;  // j*32+k
    __shared__ float Yl[32][128];  // [p*16+l][m] raw signs
    __shared__ float Zl[32][128];  // [p*16+l][n] raw signs
    __shared__ float B1[128], C1[128];
    __shared__ float cf[7];
    if (t < 2) {
      int idx = t * 1024 + jk;
      float ys = Ysc[idx], zs = Zsc[idx];
      cf[t] = Acoef[idx * 4 + 0] * ys * zs;
      cf[2 + t] = Acoef[idx * 4 + 1] * ys;
      cf[4 + t] = Acoef[idx * 4 + 2] * zs;
    } else if (t == 2) {
      cf[6] = Acoef[jk * 4 + 3] + Acoef[(1024 + jk) * 4 + 3];
    }
#pragma unroll
    for (int rep = 0; rep < 4; ++rep) {
      int q = t + rep * 256;
      int p = q >> 9, m = (q >> 2) & 127, l0 = (q & 3) * 4;
      float4 v = *(const float4*)(Ysg + (size_t)(p * 1024 + jk) * 2048 + m * 16 + l0);
      Yl[p * 16 + l0 + 0][m] = v.x;
      Yl[p * 16 + l0 + 1][m] = v.y;
      Yl[p * 16 + l0 + 2][m] = v.z;
      Yl[p * 16 + l0 + 3][m] = v.w;
    }
#pragma unroll
    for (int rep = 0; rep < 4; ++rep) {
      int q = t + rep * 256;
      int p = q >> 9, l = (q >> 5) & 15, n0 = (q & 31) * 4;
      float4 v = *(const float4*)(Zsg + (size_t)(p * 1024 + jk) * 2048 + l * 128 + n0);
      *(float4*)&Zl[p * 16 + l][n0] = v;
    }
    __syncthreads();
    if (t < 128) {
      float s = 0.f;
#pragma unroll
      for (int pl = 0; pl < 32; ++pl) s += cf[2 + (pl >> 4)] * Yl[pl][t];
      B1[t] = s;
    } else {
      int n = t - 128;
      float s = 0.f;
#pragma unroll
      for (int pl = 0; pl < 32; ++pl) s += cf[4 + (pl >> 4)] * Zl[pl][n];
      C1[n] = s;
    }
    __syncthreads();
    const int m0 = (t >> 3) * 4;
    const int n0 = (t & 7) * 4;
    float acc[4][16];
#pragma unroll
    for (int i = 0; i < 4; ++i)
#pragma unroll
      for (int g = 0; g < 16; ++g) acc[i][g] = 0.f;
    for (int pl = 0; pl < 32; ++pl) {
      float c = cf[pl >> 4];
      float4 y = *(const float4*)&Yl[pl][m0];
      float ym[4] = {y.x * c, y.y * c, y.z * c, y.w * c};
      float zr[16];
#pragma unroll
      for (int g = 0; g < 4; ++g) {
        float4 z = *(const float4*)&Zl[pl][n0 + g * 32];
        zr[g * 4 + 0] = z.x; zr[g * 4 + 1] = z.y; zr[g * 4 + 2] = z.z; zr[g * 4 + 3] = z.w;
      }
#pragma unroll
      for (int i = 0; i < 4; ++i)
#pragma unroll
        for (int g = 0; g < 16; ++g) acc[i][g] = fmaf(ym[i], zr[g], acc[i][g]);
    }
    const int j = jk >> 5, k = jk & 31;
    const float Dv = cf[6];
#pragma unroll
    for (int i = 0; i < 4; ++i) {
      int m = m0 + i;
      float bm = B1[m] + Dv;
      size_t rowoff = (size_t)(j * 128 + m) * 4096 + (size_t)(k * 128);
#pragma unroll
      for (int g = 0; g < 4; ++g) {
        int n = n0 + g * 32;
        ushort4 o = make_ushort4(f2bf(acc[i][g * 4 + 0] + bm + C1[n + 0]),
                                 f2bf(acc[i][g * 4 + 1] + bm + C1[n + 1]),
                                 f2bf(acc[i][g * 4 + 2] + bm + C1[n + 2]),
                                 f2bf(acc[i][g * 4 + 3] + bm + C1[n + 3]));
        *(ushort4*)(W + rowoff + n) = o;
      }
    }
  } else {
    // ---- quantize (with in-block redundant scale reduce) ----
    const int qb = blockIdx.x - 1024;
    float2 v2 = ((const float2*)part)[t];  // 256 float2 = 512 partials
    float mn = v2.x, mx = v2.y;
#pragma unroll
    for (int o = 32; o > 0; o >>= 1) {
      mn = fminf(mn, __shfl_down(mn, o));
      mx = fmaxf(mx, __shfl_down(mx, o));
    }
    __shared__ float smn2[4], smx2[4], ssc[1];
    int lane = t & 63, w = t >> 6;
    if (lane == 0) { smn2[w] = mn; smx2[w] = mx; }
    __syncthreads();
    if (t == 0) {
      mn = fminf(fminf(smn2[0], smn2[1]), fminf(smn2[2], smn2[3]));
      mx = fmaxf(fmaxf(smx2[0], smx2[1]), fmaxf(smx2[2], smx2[3]));
      ssc[0] = fmaxf((mx - mn) / 254.0f, 1e-8f);
      if (qb == 0) scl[0] = ssc[0];
    }
    __syncthreads();
    const float s = ssc[0];
    int i = qb * 256 + t;
    float4 v = ((const float4*)x)[i];
    float a = fminf(fmaxf(rintf(v.x / s), -127.f), 127.f);
    float b = fminf(fmaxf(rintf(v.y / s), -127.f), 127.f);
    float c = fminf(fmaxf(rintf(v.z / s), -127.f), 127.f);
    float d = fminf(fmaxf(rintf(v.w / s), -127.f), 127.f);
    ((ushort4*)xq)[i] = make_ushort4(f2bf(a), f2bf(b), f2bf(c), f2bf(d));
  }
}

// ---------------- 3) GEMM split-K4: raw acc; BM=256,BN=128,BK=64 ----------------
// Grid 256 = 2(bm) x 32(bn) x 4(sk). 8 waves 4x2 -> wave tile 64x64 (Fm=Fn=4).
// Ring-3 LDS (144KB), stage-ahead-2, counted vmcnt(12) (6 loads/wave/iter).
// XOR swizzle byte^((row&7)<<4) on global source col + on LDS reads.
// sk==0 writes raw f32 acc to out; sk>0 writes bf16 partial to P[sk-1].
__global__ __launch_bounds__(512) void k_gemm(const unsigned short* __restrict__ Xq,
                                              const unsigned short* __restrict__ W,
                                              float* __restrict__ out,
                                              unsigned short* __restrict__ P) {
  __shared__ unsigned short Al[3][256 * 64];  // 3 x 32KB
  __shared__ unsigned short Bl[3][128 * 64];  // 3 x 16KB
  const int t = threadIdx.x, lane = t & 63, wid = t >> 6;  // wid 0..7
  // XCD-chunked bijective swizzle (grid 256 % 8 == 0)
  const int wg = (blockIdx.x & 7) * 32 + (blockIdx.x >> 3);
  const int bn = wg >> 3;         // 0..31 (XCD owns 4 consecutive bn -> 4MB W panel)
  const int sk = (wg >> 1) & 3;   // K slice
  const int bm = wg & 1;          // 0..1
  const int wm = wid >> 1, wn = wid & 1;  // wave tile 64x64
  const int kbase = sk * 1024;
  f32x4 acc[4][4];
#pragma unroll
  for (int a = 0; a < 4; ++a)
#pragma unroll
    for (int b = 0; b < 4; ++b) acc[a][b] = (f32x4)(0.f);

  const int lr = lane >> 3;         // row-in-chunk 0..7
  const int lcb = (lane & 7) * 16;  // byte col in 128B row

  auto STAGE = [&](int buf, int kt) {
    const int k0 = kbase + kt * 64;
    // A tile 256x64: 32 chunks of 1KB, 4 per wave
#pragma unroll
    for (int c = 0; c < 4; ++c) {
      int chunk = wid * 4 + c;
      int r = chunk * 8 + lr;
      int colb = lcb ^ ((r & 7) << 4);
      load_lds16(Xq + ((size_t)(bm * 256 + r) << 12) + k0 + (colb >> 1), &Al[buf][chunk * 512]);
    }
    // B tile 128x64: 16 chunks, 2 per wave
#pragma unroll
    for (int c = 0; c < 2; ++c) {
      int chunk = wid * 2 + c;
      int r = chunk * 8 + lr;
      int colb = lcb ^ ((r & 7) << 4);
      load_lds16(W + ((size_t)(bn * 128 + r) << 12) + k0 + (colb >> 1), &Bl[buf][chunk * 512]);
    }
  };

  auto COMPUTE = [&](int buf) {
#pragma unroll
    for (int ks = 0; ks < 2; ++ks) {
      bf16x8 af[4], bfr[4];
#pragma unroll
      for (int fm = 0; fm < 4; ++fm) {
        int r = wm * 64 + fm * 16 + (lane & 15);
        int colb = (ks * 64 + ((lane >> 4) * 16)) ^ ((r & 7) << 4);
        af[fm] = *(const bf16x8*)((const char*)&Al[buf][0] + r * 128 + colb);
      }
#pragma unroll
      for (int fn = 0; fn < 4; ++fn) {
        int r = wn * 64 + fn * 16 + (lane & 15);
        int colb = (ks * 64 + ((lane >> 4) * 16)) ^ ((r & 7) << 4);
        bfr[fn] = *(const bf16x8*)((const char*)&Bl[buf][0] + r * 128 + colb);
      }
#pragma unroll
      for (int fm = 0; fm < 4; ++fm)
#pragma unroll
        for (int fn = 0; fn < 4; ++fn)
          acc[fm][fn] = __builtin_amdgcn_mfma_f32_16x16x32_bf16(af[fm], bfr[fn], acc[fm][fn], 0, 0, 0);
    }
  };

  // prologue: fill 2 buffers (12 loads outstanding per wave)
  STAGE(0, 0);
  STAGE(1, 1);
  int b0 = 2;  // buffer to stage this iter = (t+2)%3
  for (int it = 0; it < 16; ++it) {
    STAGE(b0, (it + 2) & 15);  // tail iters re-stage dummy (buffer never read)
    __builtin_amdgcn_sched_barrier(0);
    asm volatile("s_waitcnt vmcnt(12)" ::: "memory");  // stage(it) landed; 12 in flight
    __builtin_amdgcn_sched_barrier(0);
    __builtin_amdgcn_s_barrier();                      // buf[it%3] ready for all waves
    __builtin_amdgcn_sched_barrier(0);
    int cb = b0 + 1;                                   // (it)%3 == (b0+1)%3
    if (cb >= 3) cb -= 3;
    COMPUTE(cb);
    __builtin_amdgcn_sched_barrier(0);
    __builtin_amdgcn_s_barrier();                      // reads done before buf reuse
    b0 = cb;  // next stage buffer = (it+3)%3 = (it)%3 = cb
  }

  // epilogue: raw accumulators (scale+bias applied by k_epi)
  if (sk == 0) {
#pragma unroll
    for (int fn = 0; fn < 4; ++fn) {
      int col = bn * 128 + wn * 64 + fn * 16 + (lane & 15);
#pragma unroll
      for (int fm = 0; fm < 4; ++fm) {
#pragma unroll
        for (int i = 0; i < 4; ++i) {
          int row = bm * 256 + wm * 64 + fm * 16 + (lane >> 4) * 4 + i;
          out[(size_t)row * 4096 + col] = acc[fm][fn][i];
        }
      }
    }
  } else {
    unsigned short* Pk = P + (size_t)(sk - 1) * 2097152;
#pragma unroll
    for (int fn = 0; fn < 4; ++fn) {
      int col = bn * 128 + wn * 64 + fn * 16 + (lane & 15);
#pragma unroll
      for (int fm = 0; fm < 4; ++fm) {
#pragma unroll
        for (int i = 0; i < 4; ++i) {
          int row = bm * 256 + wm * 64 + fm * 16 + (lane >> 4) * 4 + i;
          Pk[(size_t)row * 4096 + col] = f2bf(acc[fm][fn][i]);
        }
      }
    }
  }
}

// ---------------- 4) epilogue: out = (raw + sum partials) * s + bias ----------------
__global__ __launch_bounds__(256) void k_epi(float* __restrict__ out,
                                             const unsigned short* __restrict__ P,
                                             const float* __restrict__ scl,
                                             const float* __restrict__ bias) {
  int i4 = blockIdx.x * 256 + threadIdx.x;  // 524288 threads, 4 f32 each
  const float s = scl[0];
  float4 r = ((const float4*)out)[i4];
  float4 bv = ((const float4*)bias)[i4 & 1023];
  float sx = r.x, sy = r.y, sz = r.z, sw = r.w;
#pragma unroll
  for (int k = 0; k < 3; ++k) {
    ushort4 p = ((const ushort4*)(P + (size_t)k * 2097152))[i4];
    sx += bf2f(p.x); sy += bf2f(p.y); sz += bf2f(p.z); sw += bf2f(p.w);
  }
  ((float4*)out)[i4] = make_float4(sx * s + bv.x, sy * s + bv.y, sz * s + bv.z, sw * s + bv.w);
}

// ---------------- fallback GEMM (R3, used if ws too small for partials) ----------------
__global__ __launch_bounds__(512) void k_gemm_fb(const unsigned short* __restrict__ Xq,
                                                 const unsigned short* __restrict__ W,
                                                 const float* __restrict__ scl,
                                                 const float* __restrict__ bias,
                                                 float* __restrict__ out) {
  __shared__ unsigned short Al[4][128 * 64];
  __shared__ unsigned short Bl[4][64 * 64];
  const int t = threadIdx.x, lane = t & 63, wid = t >> 6;
  const int wg = (blockIdx.x & 7) * 32 + (blockIdx.x >> 3);
  const int bm = wg & 3;
  const int bn = wg >> 2;
  const int wm = wid >> 1, wn = wid & 1;
  f32x4 acc[2][2];
#pragma unroll
  for (int a = 0; a < 2; ++a)
#pragma unroll
    for (int b = 0; b < 2; ++b) acc[a][b] = (f32x4)(0.f);
  const int lr = lane >> 3;
  const int lcb = (lane & 7) * 16;
  auto STAGE = [&](int buf, int kt) {
    const int k0 = kt * 64;
#pragma unroll
    for (int c = 0; c < 2; ++c) {
      int chunk = wid * 2 + c;
      int r = chunk * 8 + lr;
      int colb = lcb ^ ((r & 7) << 4);
      load_lds16(Xq + ((size_t)(bm * 128 + r) << 12) + k0 + (colb >> 1), &Al[buf][chunk * 512]);
    }
    {
      int r = wid * 8 + lr;
      int colb = lcb ^ ((r & 7) << 4);
      load_lds16(W + ((size_t)(bn * 64 + r) << 12) + k0 + (colb >> 1), &Bl[buf][wid * 512]);
    }
  };
  auto COMPUTE = [&](int buf) {
#pragma unroll
    for (int ks = 0; ks < 2; ++ks) {
      bf16x8 af[2], bfr[2];
#pragma unroll
      for (int fm = 0; fm < 2; ++fm) {
        int r = wm * 32 + fm * 16 + (lane & 15);
        int colb = (ks * 64 + ((lane >> 4) * 16)) ^ ((r & 7) << 4);
        af[fm] = *(const bf16x8*)((const char*)&Al[buf][0] + r * 128 + colb);
      }
#pragma unroll
      for (int fn = 0; fn < 2; ++fn) {
        int r = wn * 32 + fn * 16 + (lane & 15);
        int colb = (ks * 64 + ((lane >> 4) * 16)) ^ ((r & 7) << 4);
        bfr[fn] = *(const bf16x8*)((const char*)&Bl[buf][0] + r * 128 + colb);
      }
#pragma unroll
      for (int fm = 0; fm < 2; ++fm)
#pragma unroll
        for (int fn = 0; fn < 2; ++fn)
          acc[fm][fn] = __builtin_amdgcn_mfma_f32_16x16x32_bf16(af[fm], bfr[fn], acc[fm][fn], 0, 0, 0);
    }
  };
  STAGE(0, 0); STAGE(1, 1); STAGE(2, 2);
  for (int t64 = 0; t64 < 64; ++t64) {
    STAGE((t64 + 3) & 3, (t64 + 3) & 63);
    __builtin_amdgcn_sched_barrier(0);
    asm volatile("s_waitcnt vmcnt(9)" ::: "memory");
    __builtin_amdgcn_sched_barrier(0);
    __builtin_amdgcn_s_barrier();
    __builtin_amdgcn_sched_barrier(0);
    COMPUTE(t64 & 3);
    __builtin_amdgcn_sched_barrier(0);
    __builtin_amdgcn_s_barrier();
  }
  const float s = scl[0];
#pragma unroll
  for (int fn = 0; fn < 2; ++fn) {
    int col = bn * 64 + wn * 32 + fn * 16 + (lane & 15);
    float bv = bias[col];
#pragma unroll
    for (int fm = 0; fm < 2; ++fm) {
#pragma unroll
      for (int i = 0; i < 4; ++i) {
        int row = bm * 128 + wm * 32 + fm * 16 + (lane >> 4) * 4 + i;
        out[(size_t)row * 4096 + col] = acc[fm][fn][i] * s + bv;
      }
    }
  }
}

extern "C" void kernel_launch(void* const* d_in, const int* in_sizes, int n_in,
                              void* d_out, int out_size, void* d_ws, size_t ws_size,
                              hipStream_t stream) {
  const float* x    = (const float*)d_in[0];  // (1,512,4096)
  const float* Ysg  = (const float*)d_in[1];  // (2,32,32,128,16)
  const float* Zsg  = (const float*)d_in[2];  // (2,32,32,16,128)
  const float* Ysc  = (const float*)d_in[3];  // (2,32,32)
  const float* Zsc  = (const float*)d_in[4];  // (2,32,32)
  const float* A    = (const float*)d_in[5];  // (2,32,32,4)
  const float* bias = (const float*)d_in[6];  // (4096,)
  float* out = (float*)d_out;

  char* ws = (char*)d_ws;
  float* scl  = (float*)ws;                  // [0] act_scale
  float* part = (float*)(ws + 256);          // 512 f32 partials
  unsigned short* Xq = (unsigned short*)(ws + 65536);                    // 4MB bf16
  unsigned short* W  = (unsigned short*)(ws + 65536 + (size_t)4194304);  // 32MB bf16
  unsigned short* P  = (unsigned short*)(ws + 65536 + (size_t)4194304 + (size_t)33554432);  // 12MB bf16 partials

  k_minmax_part<<<dim3(256), dim3(256), 0, stream>>>(x, part);
  k_fused<<<dim3(3072), dim3(256), 0, stream>>>(x, part, Ysg, Zsg, Ysc, Zsc, A, scl, Xq, W);
  if (ws_size >= (size_t)65536 + 4194304 + 33554432 + 12582912) {
    k_gemm<<<dim3(256), dim3(512), 0, stream>>>(Xq, W, out, P);
    k_epi<<<dim3(2048), dim3(256), 0, stream>>>(out, P, scl, bias);
  } else {
    k_gemm_fb<<<dim3(256), dim3(512), 0, stream>>>(Xq, W, scl, bias, out);
  }
}

// Round 5
// 56.932 us; speedup vs baseline: 1.5411x; 1.1450x over previous
//
#include <hip/hip_runtime.h>
#include <hip/hip_bf16.h>

// BQQ dims: P=2, J=32, K=32, M=128, L=16, N=128; B=512; in=kn=4096; out=jm=4096
typedef __attribute__((ext_vector_type(4))) float f32x4;
typedef __attribute__((ext_vector_type(8))) short bf16x8;
typedef __attribute__((ext_vector_type(4))) unsigned int u32x4;

#define GLOBAL_AS __attribute__((address_space(1)))
#define LDS_AS __attribute__((address_space(3)))

static __device__ __forceinline__ unsigned short f2bf(float f) {
  __hip_bfloat16 h = __float2bfloat16(f);
  return __builtin_bit_cast(unsigned short, h);
}
static __device__ __forceinline__ float bf2f(unsigned short u) {
  unsigned int v = ((unsigned int)u) << 16;
  return __builtin_bit_cast(float, v);
}
static __device__ __forceinline__ void load_lds16(const void* g, void* l) {
  __builtin_amdgcn_global_load_lds((GLOBAL_AS void*)g, (LDS_AS void*)l, 16, 0, 0);
}

// ---------------- 1) per-block min/max of input (2M f32), 256 blocks ----------------
__global__ __launch_bounds__(256) void k_minmax_part(const float* __restrict__ x,
                                                     float* __restrict__ part) {
  int tid = blockIdx.x * 256 + threadIdx.x;  // 65536 threads, 8 float4 each
  const float4* xv = (const float4*)x;
  float mn = 3.4e38f, mx = -3.4e38f;
#pragma unroll
  for (int rep = 0; rep < 8; ++rep) {
    float4 v = xv[tid + rep * 65536];
    mn = fminf(mn, fminf(fminf(v.x, v.y), fminf(v.z, v.w)));
    mx = fmaxf(mx, fmaxf(fmaxf(v.x, v.y), fmaxf(v.z, v.w)));
  }
#pragma unroll
  for (int o = 32; o > 0; o >>= 1) {
    mn = fminf(mn, __shfl_down(mn, o));
    mx = fmaxf(mx, __shfl_down(mx, o));
  }
  __shared__ float smn[4], smx[4];
  int lane = threadIdx.x & 63, w = threadIdx.x >> 6;
  if (lane == 0) { smn[w] = mn; smx[w] = mx; }
  __syncthreads();
  if (threadIdx.x == 0) {
    mn = fminf(fminf(smn[0], smn[1]), fminf(smn[2], smn[3]));
    mx = fmaxf(fmaxf(smx[0], smx[1]), fmaxf(smx[2], smx[3]));
    part[2 * blockIdx.x] = mn;
    part[2 * blockIdx.x + 1] = mx;
  }
}

// ---------------- 2) fused: blocks 0..1023 = build W (MFMA); 1024..3071 = quantize ----------------
// W[jm][kn] = sum_p cf0_p*(Ysign @ Zsign) + B1[m] + C1[n] + D   (bf16)
// Y staged as bf16 with cf0_p folded, layout [p*128+m][l] (a_frag native).
// Z transposed to [n][pl] packed bf16 (pitch 72B) = b_frag native.
// One 16x16x32 MFMA per output tile (K=32 = all pl at once).
__global__ __launch_bounds__(256) void k_fused(const float* __restrict__ x,
                                               const float* __restrict__ part,
                                               const float* __restrict__ Ysg,
                                               const float* __restrict__ Zsg,
                                               const float* __restrict__ Ysc,
                                               const float* __restrict__ Zsc,
                                               const float* __restrict__ Acoef,
                                               float* __restrict__ scl,
                                               unsigned short* __restrict__ xq,
                                               unsigned short* __restrict__ W) {
  const int t = threadIdx.x;
  if (blockIdx.x < 1024) {
    // ---- build_w (MFMA) ----
    const int jk = blockIdx.x;  // j*32+k
    __shared__ unsigned short Yb[2 * 128 * 24];  // [p*128+m][24] halves; data in [0..16)
    __shared__ unsigned short Zb[128 * 36];      // [n][36] halves; data pl in [0..32)
    __shared__ float B1p[2][128];                // per-p row sign-sums
    __shared__ float C1[128];
    // per-thread coefficients (broadcast loads)
    float cf0[2], cf2[2], cf4[2];
    float Dv;
    {
      float ys0 = Ysc[jk], zs0 = Zsc[jk], ys1 = Ysc[1024 + jk], zs1 = Zsc[1024 + jk];
      const float* A0p = Acoef + (size_t)jk * 4;
      const float* A1p = Acoef + (size_t)(1024 + jk) * 4;
      cf0[0] = A0p[0] * ys0 * zs0; cf0[1] = A1p[0] * ys1 * zs1;
      cf2[0] = A0p[1] * ys0;       cf2[1] = A1p[1] * ys1;
      cf4[0] = A0p[2] * zs0;       cf4[1] = A1p[2] * zs1;
      Dv = A0p[3] + A1p[3];
    }
    // stage Y: [p][m][l] f32 -> Yb[(p*128+m)*24 + l] bf16*cf0; B1p via quad shuffle
#pragma unroll
    for (int rep = 0; rep < 4; ++rep) {
      int q = rep * 256 + t;
      int l0 = (q & 3) * 4, m = (q >> 2) & 127, p = q >> 9;
      float4 v = *(const float4*)(Ysg + (size_t)(p * 1024 + jk) * 2048 + m * 16 + l0);
      float s4 = v.x + v.y + v.z + v.w;
      s4 += __shfl_xor(s4, 1);
      s4 += __shfl_xor(s4, 2);
      if ((t & 3) == 0) B1p[p][m] = s4;
      float c0 = cf0[p];
      ushort4 o = make_ushort4(f2bf(c0 * v.x), f2bf(c0 * v.y), f2bf(c0 * v.z), f2bf(c0 * v.w));
      *(ushort4*)&Yb[(p * 128 + m) * 24 + l0] = o;
    }
    // stage Z transposed: [p][l][n] f32 -> Zb[n*36 + p*16+l] bf16 (raw sign)
#pragma unroll
    for (int rep = 0; rep < 4; ++rep) {
      int q = rep * 256 + t;
      int n0 = (q & 31) * 4, l = (q >> 5) & 15, p = q >> 9;
      float4 v = *(const float4*)(Zsg + (size_t)(p * 1024 + jk) * 2048 + l * 128 + n0);
      int pl = p * 16 + l;
      Zb[(n0 + 0) * 36 + pl] = f2bf(v.x);
      Zb[(n0 + 1) * 36 + pl] = f2bf(v.y);
      Zb[(n0 + 2) * 36 + pl] = f2bf(v.z);
      Zb[(n0 + 3) * 36 + pl] = f2bf(v.w);
    }
    __syncthreads();
    if (t < 128) {
      float s0 = 0.f, s1 = 0.f;
#pragma unroll
      for (int l = 0; l < 16; ++l) {
        s0 += bf2f(Zb[t * 36 + l]);
        s1 += bf2f(Zb[t * 36 + 16 + l]);
      }
      C1[t] = cf4[0] * s0 + cf4[1] * s1;
    }
    __syncthreads();
    // MFMA: 4 waves 2x2, wave tile 64x64, 16 tiles x 1 mfma (K=32)
    const int lane = t & 63, wid = t >> 6;
    const int wm = wid >> 1, wn = wid & 1;
    const int grp = lane >> 4;
    bf16x8 af[4], bfr[4];
#pragma unroll
    for (int fm = 0; fm < 4; ++fm) {
      int m = wm * 64 + fm * 16 + (lane & 15);
      af[fm] = *(const bf16x8*)((const char*)Yb + ((grp >> 1) * 128 + m) * 48 + (grp & 1) * 16);
    }
#pragma unroll
    for (int fn = 0; fn < 4; ++fn) {
      int n = wn * 64 + fn * 16 + (lane & 15);
      const char* zp = (const char*)Zb + n * 72 + grp * 16;
      uint2 z0 = *(const uint2*)zp;
      uint2 z1 = *(const uint2*)(zp + 8);
      u32x4 zw; zw[0] = z0.x; zw[1] = z0.y; zw[2] = z1.x; zw[3] = z1.y;
      bfr[fn] = __builtin_bit_cast(bf16x8, zw);
    }
    f32x4 acc[4][4];
#pragma unroll
    for (int fm = 0; fm < 4; ++fm)
#pragma unroll
      for (int fn = 0; fn < 4; ++fn)
        acc[fm][fn] = __builtin_amdgcn_mfma_f32_16x16x32_bf16(af[fm], bfr[fn], (f32x4)(0.f), 0, 0, 0);
    // epilogue: + B1 + C1 + D, cvt, store
    const int j = jk >> 5, k = jk & 31;
    float c1v[4];
#pragma unroll
    for (int fn = 0; fn < 4; ++fn) c1v[fn] = C1[wn * 64 + fn * 16 + (lane & 15)];
#pragma unroll
    for (int fm = 0; fm < 4; ++fm) {
#pragma unroll
      for (int i = 0; i < 4; ++i) {
        int row = wm * 64 + fm * 16 + (grp)*4 + i;
        float b1v = cf2[0] * B1p[0][row] + cf2[1] * B1p[1][row] + Dv;
        size_t rowoff = (size_t)(j * 128 + row) * 4096 + (size_t)(k * 128);
#pragma unroll
        for (int fn = 0; fn < 4; ++fn) {
          int col = wn * 64 + fn * 16 + (lane & 15);
          W[rowoff + col] = f2bf(acc[fm][fn][i] + b1v + c1v[fn]);
        }
      }
    }
  } else {
    // ---- quantize (with in-block redundant scale reduce) ----
    const int qb = blockIdx.x - 1024;
    float2 v2 = ((const float2*)part)[t];  // 256 float2 = 512 partials
    float mn = v2.x, mx = v2.y;
#pragma unroll
    for (int o = 32; o > 0; o >>= 1) {
      mn = fminf(mn, __shfl_down(mn, o));
      mx = fmaxf(mx, __shfl_down(mx, o));
    }
    __shared__ float smn2[4], smx2[4], ssc[1];
    int lane = t & 63, w = t >> 6;
    if (lane == 0) { smn2[w] = mn; smx2[w] = mx; }
    __syncthreads();
    if (t == 0) {
      mn = fminf(fminf(smn2[0], smn2[1]), fminf(smn2[2], smn2[3]));
      mx = fmaxf(fmaxf(smx2[0], smx2[1]), fmaxf(smx2[2], smx2[3]));
      ssc[0] = fmaxf((mx - mn) / 254.0f, 1e-8f);
      if (qb == 0) scl[0] = ssc[0];
    }
    __syncthreads();
    const float s = ssc[0];
    int i = qb * 256 + t;
    float4 v = ((const float4*)x)[i];
    float a = fminf(fmaxf(rintf(v.x / s), -127.f), 127.f);
    float b = fminf(fmaxf(rintf(v.y / s), -127.f), 127.f);
    float c = fminf(fmaxf(rintf(v.z / s), -127.f), 127.f);
    float d = fminf(fmaxf(rintf(v.w / s), -127.f), 127.f);
    ((ushort4*)xq)[i] = make_ushort4(f2bf(a), f2bf(b), f2bf(c), f2bf(d));
  }
}

// ---------------- 3) GEMM split-K4: raw acc; BM=256,BN=128,BK=64 ----------------
// Grid 256 = 2(bm) x 32(bn) x 4(sk). 8 waves 4x2 -> wave tile 64x64 (Fm=Fn=4).
// Ring-3 LDS (144KB), stage-ahead-2, counted vmcnt(12) (6 loads/wave/iter).
// XOR swizzle byte^((row&7)<<4) on global source col + on LDS reads.
// sk==0 writes raw f32 acc to out; sk>0 writes bf16 partial to P[sk-1].
__global__ __launch_bounds__(512) void k_gemm(const unsigned short* __restrict__ Xq,
                                              const unsigned short* __restrict__ W,
                                              float* __restrict__ out,
                                              unsigned short* __restrict__ P) {
  __shared__ unsigned short Al[3][256 * 64];  // 3 x 32KB
  __shared__ unsigned short Bl[3][128 * 64];  // 3 x 16KB
  const int t = threadIdx.x, lane = t & 63, wid = t >> 6;  // wid 0..7
  // XCD-chunked bijective swizzle (grid 256 % 8 == 0)
  const int wg = (blockIdx.x & 7) * 32 + (blockIdx.x >> 3);
  const int bn = wg >> 3;         // 0..31 (XCD owns 4 consecutive bn -> 4MB W panel)
  const int sk = (wg >> 1) & 3;   // K slice
  const int bm = wg & 1;          // 0..1
  const int wm = wid >> 1, wn = wid & 1;  // wave tile 64x64
  const int kbase = sk * 1024;
  f32x4 acc[4][4];
#pragma unroll
  for (int a = 0; a < 4; ++a)
#pragma unroll
    for (int b = 0; b < 4; ++b) acc[a][b] = (f32x4)(0.f);

  const int lr = lane >> 3;         // row-in-chunk 0..7
  const int lcb = (lane & 7) * 16;  // byte col in 128B row

  auto STAGE = [&](int buf, int kt) {
    const int k0 = kbase + kt * 64;
#pragma unroll
    for (int c = 0; c < 4; ++c) {
      int chunk = wid * 4 + c;
      int r = chunk * 8 + lr;
      int colb = lcb ^ ((r & 7) << 4);
      load_lds16(Xq + ((size_t)(bm * 256 + r) << 12) + k0 + (colb >> 1), &Al[buf][chunk * 512]);
    }
#pragma unroll
    for (int c = 0; c < 2; ++c) {
      int chunk = wid * 2 + c;
      int r = chunk * 8 + lr;
      int colb = lcb ^ ((r & 7) << 4);
      load_lds16(W + ((size_t)(bn * 128 + r) << 12) + k0 + (colb >> 1), &Bl[buf][chunk * 512]);
    }
  };

  auto COMPUTE = [&](int buf) {
#pragma unroll
    for (int ks = 0; ks < 2; ++ks) {
      bf16x8 af[4], bfr[4];
#pragma unroll
      for (int fm = 0; fm < 4; ++fm) {
        int r = wm * 64 + fm * 16 + (lane & 15);
        int colb = (ks * 64 + ((lane >> 4) * 16)) ^ ((r & 7) << 4);
        af[fm] = *(const bf16x8*)((const char*)&Al[buf][0] + r * 128 + colb);
      }
#pragma unroll
      for (int fn = 0; fn < 4; ++fn) {
        int r = wn * 64 + fn * 16 + (lane & 15);
        int colb = (ks * 64 + ((lane >> 4) * 16)) ^ ((r & 7) << 4);
        bfr[fn] = *(const bf16x8*)((const char*)&Bl[buf][0] + r * 128 + colb);
      }
#pragma unroll
      for (int fm = 0; fm < 4; ++fm)
#pragma unroll
        for (int fn = 0; fn < 4; ++fn)
          acc[fm][fn] = __builtin_amdgcn_mfma_f32_16x16x32_bf16(af[fm], bfr[fn], acc[fm][fn], 0, 0, 0);
    }
  };

  STAGE(0, 0);
  STAGE(1, 1);
  int b0 = 2;  // buffer to stage this iter
  for (int it = 0; it < 16; ++it) {
    STAGE(b0, (it + 2) & 15);  // tail iters re-stage dummy (buffer never read)
    __builtin_amdgcn_sched_barrier(0);
    asm volatile("s_waitcnt vmcnt(12)" ::: "memory");  // stage(it) landed; 12 in flight
    __builtin_amdgcn_sched_barrier(0);
    __builtin_amdgcn_s_barrier();                      // buf[it%3] ready for all waves
    __builtin_amdgcn_sched_barrier(0);
    int cb = b0 + 1;
    if (cb >= 3) cb -= 3;
    COMPUTE(cb);
    __builtin_amdgcn_sched_barrier(0);
    __builtin_amdgcn_s_barrier();                      // reads done before buf reuse
    b0 = cb;
  }

  if (sk == 0) {
#pragma unroll
    for (int fn = 0; fn < 4; ++fn) {
      int col = bn * 128 + wn * 64 + fn * 16 + (lane & 15);
#pragma unroll
      for (int fm = 0; fm < 4; ++fm) {
#pragma unroll
        for (int i = 0; i < 4; ++i) {
          int row = bm * 256 + wm * 64 + fm * 16 + (lane >> 4) * 4 + i;
          out[(size_t)row * 4096 + col] = acc[fm][fn][i];
        }
      }
    }
  } else {
    unsigned short* Pk = P + (size_t)(sk - 1) * 2097152;
#pragma unroll
    for (int fn = 0; fn < 4; ++fn) {
      int col = bn * 128 + wn * 64 + fn * 16 + (lane & 15);
#pragma unroll
      for (int fm = 0; fm < 4; ++fm) {
#pragma unroll
        for (int i = 0; i < 4; ++i) {
          int row = bm * 256 + wm * 64 + fm * 16 + (lane >> 4) * 4 + i;
          Pk[(size_t)row * 4096 + col] = f2bf(acc[fm][fn][i]);
        }
      }
    }
  }
}

// ---------------- 4) epilogue: out = (raw + sum partials) * s + bias ----------------
__global__ __launch_bounds__(256) void k_epi(float* __restrict__ out,
                                             const unsigned short* __restrict__ P,
                                             const float* __restrict__ scl,
                                             const float* __restrict__ bias) {
  int i4 = blockIdx.x * 256 + threadIdx.x;  // 524288 threads, 4 f32 each
  const float s = scl[0];
  float4 r = ((const float4*)out)[i4];
  float4 bv = ((const float4*)bias)[i4 & 1023];
  float sx = r.x, sy = r.y, sz = r.z, sw = r.w;
#pragma unroll
  for (int k = 0; k < 3; ++k) {
    ushort4 p = ((const ushort4*)(P + (size_t)k * 2097152))[i4];
    sx += bf2f(p.x); sy += bf2f(p.y); sz += bf2f(p.z); sw += bf2f(p.w);
  }
  ((float4*)out)[i4] = make_float4(sx * s + bv.x, sy * s + bv.y, sz * s + bv.z, sw * s + bv.w);
}

// ---------------- fallback GEMM (used if ws too small for partials) ----------------
__global__ __launch_bounds__(512) void k_gemm_fb(const unsigned short* __restrict__ Xq,
                                                 const unsigned short* __restrict__ W,
                                                 const float* __restrict__ scl,
                                                 const float* __restrict__ bias,
                                                 float* __restrict__ out) {
  __shared__ unsigned short Al[4][128 * 64];
  __shared__ unsigned short Bl[4][64 * 64];
  const int t = threadIdx.x, lane = t & 63, wid = t >> 6;
  const int wg = (blockIdx.x & 7) * 32 + (blockIdx.x >> 3);
  const int bm = wg & 3;
  const int bn = wg >> 2;
  const int wm = wid >> 1, wn = wid & 1;
  f32x4 acc[2][2];
#pragma unroll
  for (int a = 0; a < 2; ++a)
#pragma unroll
    for (int b = 0; b < 2; ++b) acc[a][b] = (f32x4)(0.f);
  const int lr = lane >> 3;
  const int lcb = (lane & 7) * 16;
  auto STAGE = [&](int buf, int kt) {
    const int k0 = kt * 64;
#pragma unroll
    for (int c = 0; c < 2; ++c) {
      int chunk = wid * 2 + c;
      int r = chunk * 8 + lr;
      int colb = lcb ^ ((r & 7) << 4);
      load_lds16(Xq + ((size_t)(bm * 128 + r) << 12) + k0 + (colb >> 1), &Al[buf][chunk * 512]);
    }
    {
      int r = wid * 8 + lr;
      int colb = lcb ^ ((r & 7) << 4);
      load_lds16(W + ((size_t)(bn * 64 + r) << 12) + k0 + (colb >> 1), &Bl[buf][wid * 512]);
    }
  };
  auto COMPUTE = [&](int buf) {
#pragma unroll
    for (int ks = 0; ks < 2; ++ks) {
      bf16x8 af[2], bfr[2];
#pragma unroll
      for (int fm = 0; fm < 2; ++fm) {
        int r = wm * 32 + fm * 16 + (lane & 15);
        int colb = (ks * 64 + ((lane >> 4) * 16)) ^ ((r & 7) << 4);
        af[fm] = *(const bf16x8*)((const char*)&Al[buf][0] + r * 128 + colb);
      }
#pragma unroll
      for (int fn = 0; fn < 2; ++fn) {
        int r = wn * 32 + fn * 16 + (lane & 15);
        int colb = (ks * 64 + ((lane >> 4) * 16)) ^ ((r & 7) << 4);
        bfr[fn] = *(const bf16x8*)((const char*)&Bl[buf][0] + r * 128 + colb);
      }
#pragma unroll
      for (int fm = 0; fm < 2; ++fm)
#pragma unroll
        for (int fn = 0; fn < 2; ++fn)
          acc[fm][fn] = __builtin_amdgcn_mfma_f32_16x16x32_bf16(af[fm], bfr[fn], acc[fm][fn], 0, 0, 0);
    }
  };
  STAGE(0, 0); STAGE(1, 1); STAGE(2, 2);
  for (int t64 = 0; t64 < 64; ++t64) {
    STAGE((t64 + 3) & 3, (t64 + 3) & 63);
    __builtin_amdgcn_sched_barrier(0);
    asm volatile("s_waitcnt vmcnt(9)" ::: "memory");
    __builtin_amdgcn_sched_barrier(0);
    __builtin_amdgcn_s_barrier();
    __builtin_amdgcn_sched_barrier(0);
    COMPUTE(t64 & 3);
    __builtin_amdgcn_sched_barrier(0);
    __builtin_amdgcn_s_barrier();
  }
  const float s = scl[0];
#pragma unroll
  for (int fn = 0; fn < 2; ++fn) {
    int col = bn * 64 + wn * 32 + fn * 16 + (lane & 15);
    float bv = bias[col];
#pragma unroll
    for (int fm = 0; fm < 2; ++fm) {
#pragma unroll
      for (int i = 0; i < 4; ++i) {
        int row = bm * 128 + wm * 32 + fm * 16 + (lane >> 4) * 4 + i;
        out[(size_t)row * 4096 + col] = acc[fm][fn][i] * s + bv;
      }
    }
  }
}

extern "C" void kernel_launch(void* const* d_in, const int* in_sizes, int n_in,
                              void* d_out, int out_size, void* d_ws, size_t ws_size,
                              hipStream_t stream) {
  const float* x    = (const float*)d_in[0];  // (1,512,4096)
  const float* Ysg  = (const float*)d_in[1];  // (2,32,32,128,16)
  const float* Zsg  = (const float*)d_in[2];  // (2,32,32,16,128)
  const float* Ysc  = (const float*)d_in[3];  // (2,32,32)
  const float* Zsc  = (const float*)d_in[4];  // (2,32,32)
  const float* A    = (const float*)d_in[5];  // (2,32,32,4)
  const float* bias = (const float*)d_in[6];  // (4096,)
  float* out = (float*)d_out;

  char* ws = (char*)d_ws;
  float* scl  = (float*)ws;                  // [0] act_scale
  float* part = (float*)(ws + 256);          // 512 f32 partials
  unsigned short* Xq = (unsigned short*)(ws + 65536);                    // 4MB bf16
  unsigned short* W  = (unsigned short*)(ws + 65536 + (size_t)4194304);  // 32MB bf16
  unsigned short* P  = (unsigned short*)(ws + 65536 + (size_t)4194304 + (size_t)33554432);  // 12MB bf16 partials

  k_minmax_part<<<dim3(256), dim3(256), 0, stream>>>(x, part);
  k_fused<<<dim3(3072), dim3(256), 0, stream>>>(x, part, Ysg, Zsg, Ysc, Zsc, A, scl, Xq, W);
  if (ws_size >= (size_t)65536 + 4194304 + 33554432 + 12582912) {
    k_gemm<<<dim3(256), dim3(512), 0, stream>>>(Xq, W, out, P);
    k_epi<<<dim3(2048), dim3(256), 0, stream>>>(out, P, scl, bias);
  } else {
    k_gemm_fb<<<dim3(256), dim3(512), 0, stream>>>(Xq, W, scl, bias, out);
  }
}